// Round 8
// baseline (12363.311 us; speedup 1.0000x reference)
//
#include <hip/hip_runtime.h>
#include <stdint.h>

// ---------------------------------------------------------------------------
// 4-layer stacked LSTM -> fanout/LeakyReLU/fanin -> LSTM -> head(sigmoid)
// persistent producer/consumer pipeline.
//
// R9 (base protocol = R5's streams; REC completely restructured):
//  * ONE 512-thread block per LSTM layer (5 REC blocks). The entire
//    recurrence runs on one CU: h exchange = LDS + s_barrier (no LLC RTs
//    in the step loop). R5's irreducible exchange chain (~2400cy) is gone.
//  * Whh quantized to int8 with PER-ROW scales (k_prep); h quantized with
//    fixed scale 1/127 (|h|<=1). Gates via mfma_i32_16x16x64_i8 (2x bf16
//    rate), exact i32 accumulation, f32 cell. Numerics ~ bf16-class.
//  * A/B fragments filled with the SAME (quad,byte)->k assignment, so the
//    contraction is layout-permutation-invariant (no K-layout risk).
//  * xg issued at step start, consumed after the MFMA block (latency hidden).
//  * h -> LLC bf16 ring for streams, drained once per 8-step chunk before
//    the per-layer chunk flag (streams' wait semantics unchanged).
//  * Streams: R5 code at 512 threads with wave<4 guards (large time margin).
// ---------------------------------------------------------------------------

#define B_ 16
#define T_ 2048
#define H_ 256
#define NG 1024
#define F_ 1024
#define CHUNK 8
#define NCH 256            // T_/CHUNK
#define WH 128             // h ring depth (steps)
#define WXG 128            // xg ring depth (steps)
#define WCH 16             // chunk-granular ring depth
#define NRECB 5
#define NBLK 41            // 5 REC + 20 XG + 8 FO + 8 FI
#define APITCH 264         // LDS row pitch (bf16 elems) for stream staging
#define WELEM 262144       // 1024*256

typedef __attribute__((ext_vector_type(4))) float f32x4;
typedef __attribute__((ext_vector_type(8))) short bf16x8;
typedef __attribute__((ext_vector_type(4))) int i32x4;
typedef unsigned long long ull;

// ---- workspace layout ----
#define OFF_XG   0ul
#define SZ_XG    (5ul*WXG*NG*B_*4ul)                 // f32 [5][128][1024][16]
#define OFF_H    (OFF_XG + SZ_XG)
#define SZ_H     (5ul*WH*B_*H_*2ul)                  // bf16 [5][128][16][256]
#define OFF_FO   (OFF_H + SZ_H)
#define SZ_FO    ((unsigned long)WCH*128ul*F_*2ul)   // bf16 [16][128][1024]
#define OFF_FI   (OFF_FO + SZ_FO)
#define SZ_FI    ((unsigned long)WCH*128ul*H_*2ul)   // bf16 [16][128][256]
#define OFF_WBF  (OFF_FI + SZ_FI)
#define SZ_WBF   (7ul*WELEM*2ul)
#define OFF_H4   (OFF_WBF + SZ_WBF)
#define OFF_FLAG (OFF_H4 + 16384ul + 256ul)
#define OFF_WQ   (OFF_FLAG + 4096ul)                 // int8 [5][1024][256]
#define SZ_WQ    (5ul*1024ul*256ul)
#define OFF_WS   (OFF_WQ + SZ_WQ)                    // f32 [5][1024] row scales

// flag word indices (64B-line padded where contended)
#define FL_PF(l)   ((l)*16)          // [5] REC chunk progress, value t+1 (8*(tc+1))
#define FL_XGF(s)  (80 + (s)*16)     // [16] slots per stage, value tc+1
#define FL_FOF     160               // [16]
#define FL_FIF     176               // [16]
#define FL_XGP(s)  (192 + (s)*4)     // [5][4] producer progress (chunks)
#define FL_FOP     212               // [8]
#define FL_FIP     220               // [8]
#define FL_N       256

#define BAR() do { asm volatile("" ::: "memory"); \
                   __builtin_amdgcn_s_barrier(); \
                   asm volatile("" ::: "memory"); } while (0)

__device__ __forceinline__ unsigned short f2bf(float f) {
  unsigned int u = __float_as_uint(f);
  u = u + 0x7fffu + ((u >> 16) & 1u);
  return (unsigned short)(u >> 16);
}
__device__ __forceinline__ float sigm_f(float x) { return 1.0f / (1.0f + __expf(-x)); }
__device__ __forceinline__ float tanh_f(float x) {
  float e = __expf(-2.0f * fabsf(x));
  float r = (1.0f - e) / (1.0f + e);
  return x >= 0.0f ? r : -r;
}
__device__ __forceinline__ unsigned ld32(const void* p) {
  return __hip_atomic_load((const unsigned*)p, __ATOMIC_RELAXED, __HIP_MEMORY_SCOPE_AGENT);
}
__device__ __forceinline__ void st32(void* p, unsigned v) {
  __hip_atomic_store((unsigned*)p, v, __ATOMIC_RELAXED, __HIP_MEMORY_SCOPE_AGENT);
}
__device__ __forceinline__ ull ld64(const void* p) {
  return __hip_atomic_load((const ull*)p, __ATOMIC_RELAXED, __HIP_MEMORY_SCOPE_AGENT);
}
__device__ __forceinline__ void st64(void* p, ull v) {
  __hip_atomic_store((ull*)p, v, __ATOMIC_RELAXED, __HIP_MEMORY_SCOPE_AGENT);
}
// spin with sleep back-off (bounded: a protocol bug -> wrong output, not a hang)
__device__ __forceinline__ void spin_ge(unsigned int* p, unsigned int tgt) {
  int n = 0;
  while (ld32(p) < tgt) {
    __builtin_amdgcn_s_sleep(1);
    if (++n > 5000000) break;
  }
}

// ---------------------------------------------------------------------------
__global__ void k_prep(const float* __restrict__ w0ih, const float* __restrict__ w1ih,
                       const float* __restrict__ foW, const float* __restrict__ fiW,
                       const float* __restrict__ w0hh, const float* __restrict__ w1hh,
                       unsigned char* ws) {
  __shared__ float red[256];
  unsigned short* wbf = (unsigned short*)(ws + OFF_WBF);
  unsigned int* flags = (unsigned int*)(ws + OFF_FLAG);
  if (blockIdx.x == 0 && threadIdx.x < FL_N) flags[threadIdx.x] = 0u;

  // quantize Whh rows to int8 with per-row scale: rows [5][1024]
  int r = blockIdx.x;
  if (r < 5120) {
    const float* src = (r < 4096) ? (w0hh + (size_t)r * H_) : (w1hh + (size_t)(r - 4096) * H_);
    float v = src[threadIdx.x];
    red[threadIdx.x] = fabsf(v);
    __syncthreads();
    for (int off = 128; off; off >>= 1) {
      if (threadIdx.x < off) red[threadIdx.x] = fmaxf(red[threadIdx.x], red[threadIdx.x + off]);
      __syncthreads();
    }
    float mx = red[0];
    float s = (mx > 0.f) ? (mx / 127.f) : 1.f;
    signed char* wq = (signed char*)(ws + OFF_WQ);
    wq[(size_t)r * H_ + threadIdx.x] = (signed char)(int)rintf(v / s);
    if (threadIdx.x == 0)
      ((float*)(ws + OFF_WS))[r] = (mx > 0.f) ? (s / 127.f) : 0.f;  // folds h scale 1/127
  }

  int gid = blockIdx.x * 256 + threadIdx.x;
  if (gid < 7 * WELEM) {
    int which = gid >> 18;
    int idx = gid & (WELEM - 1);
    float v;
    if (which < 4)       v = w0ih[(size_t)which * WELEM + idx];
    else if (which == 4) v = w1ih[idx];
    else if (which == 5) v = foW[idx];
    else                 v = fiW[idx];
    wbf[gid] = f2bf(v);
  }
}

// ---------------------------------------------------------------------------
__global__ __launch_bounds__(512, 1) void k_pipe(
    const float* __restrict__ x,
    const float* __restrict__ b0,
    const float* __restrict__ fo_b, const float* __restrict__ fi_b,
    const float* __restrict__ b1,
    unsigned char* ws)
{
  __shared__ unsigned short smem[64 * APITCH];   // 33792 B; REC reuses first 8KB as int8 h dbuf

  float*          xg_ring = (float*)(ws + OFF_XG);
  unsigned short* h_ring  = (unsigned short*)(ws + OFF_H);
  unsigned short* fo_ring = (unsigned short*)(ws + OFF_FO);
  unsigned short* fi_ring = (unsigned short*)(ws + OFF_FI);
  unsigned short* wbf     = (unsigned short*)(ws + OFF_WBF);
  float*          h4_last = (float*)(ws + OFF_H4);
  unsigned int*   flags   = (unsigned int*)(ws + OFF_FLAG);

  const int tid = threadIdx.x;
  const int lane = tid & 63;
  const int wave = tid >> 6;
  const int quad = lane >> 4;
  const int c16 = lane & 15;
  const int bid = blockIdx.x;

  if (bid < NRECB) {
    // ============ recurrent role: ONE block = ONE layer (8 waves) ============
    const int l = bid;
    const int n0 = wave * 32;              // this wave's 32 units
    signed char* wq = (signed char*)(ws + OFF_WQ) + (size_t)l * 1024 * 256;
    const float* wsc = (const float*)(ws + OFF_WS) + l * 1024;
    unsigned char* hlds = (unsigned char*)smem;   // [2][16 b][256 n] int8, XOR-swizzled

    // B-frags (int8, K=64 per MFMA -> kk=0..3) + per-row scales
    i32x4 bfr[2][4][4];
    float scl[2][4];
#pragma unroll
    for (int nt = 0; nt < 2; ++nt)
#pragma unroll
      for (int g = 0; g < 4; ++g) {
        int row = g * 256 + n0 + nt * 16 + c16;
        scl[nt][g] = wsc[row];
#pragma unroll
        for (int kk = 0; kk < 4; ++kk)
          bfr[nt][g][kk] = *(const i32x4*)(wq + (size_t)row * 256 + kk * 64 + quad * 16);
      }
    for (int i = tid; i < 1024; i += 512) ((ull*)hlds)[i] = 0ull;  // h(-1)=0 both bufs
    float cst[2][4] = {{0.f,0.f,0.f,0.f},{0.f,0.f,0.f,0.f}};
    __syncthreads();

    unsigned int* xgf  = flags + FL_XGF(l);
    unsigned int* mypf = flags + FL_PF(l);

    for (int t = 0; t < T_; ++t) {
      if ((t & 7) == 0) {
        if (wave == 0) {
          int tc = t >> 3;
          unsigned int* wp = (unsigned int*)0; unsigned wt = 0u;
          if (lane == 0) { wp = xgf + (tc & 15); wt = (unsigned)(tc + 1); }   // xg chunk ready
          else if (l < 4 && tc >= WCH) {                                      // h-ring overwrite guard
            unsigned gg = (unsigned)(tc - WCH + 1);
            if (l < 3) { if (lane >= 1 && lane <= 4) { wp = flags + FL_XGP(l + 1) + (lane - 1); wt = gg; } }
            else       { if (lane >= 1 && lane <= 8) { wp = flags + FL_FOP + (lane - 1); wt = gg; } }
          }
          if (wp) spin_ge(wp, wt);
        }
        BAR();
      }
      // xg issue (consumed after MFMA block; latency hidden)
      union { ull u[2]; float f[4]; } xgv[8];
      {
        const ull* xg8 = (const ull*)(xg_ring + ((size_t)l * WXG + (size_t)(t & 127)) * (NG * B_));
#pragma unroll
        for (int g = 0; g < 4; ++g)
#pragma unroll
          for (int nt = 0; nt < 2; ++nt) {
            size_t n8 = (size_t)(g * 256 + n0 + nt * 16 + c16) * 8 + quad * 2;
            xgv[g * 2 + nt].u[0] = ld64(xg8 + n8);
            xgv[g * 2 + nt].u[1] = ld64(xg8 + n8 + 1);
          }
      }
      // gates = h . Whh^T  (A int8 from LDS, B int8 from VGPRs, i32 acc)
      i32x4 acc[2][4];
#pragma unroll
      for (int nt = 0; nt < 2; ++nt)
#pragma unroll
        for (int g = 0; g < 4; ++g) acc[nt][g] = (i32x4){0, 0, 0, 0};
      int cbo = (t & 1) * 4096;
#pragma unroll
      for (int kk = 0; kk < 4; ++kk) {
        i32x4 a = *(const i32x4*)&hlds[cbo + ((c16 * 256 + kk * 64 + quad * 16) ^ ((c16 & 7) << 4))];
#pragma unroll
        for (int nt = 0; nt < 2; ++nt)
#pragma unroll
          for (int g = 0; g < 4; ++g)
            acc[nt][g] = __builtin_amdgcn_mfma_i32_16x16x64_i8(a, bfr[nt][g][kk], acc[nt][g], 0, 0, 0);
      }
      // cell; lane owns (b = quad*4+r, n = n0 + nt*16 + c16)
      int nbo = ((t + 1) & 1) * 4096;
      unsigned short* hrw = h_ring + ((size_t)l * WH + (size_t)(t & 127)) * (B_ * H_);
      float hv[2][4];
#pragma unroll
      for (int nt = 0; nt < 2; ++nt)
#pragma unroll
        for (int r = 0; r < 4; ++r) {
          float iv = sigm_f(scl[nt][0] * (float)acc[nt][0][r] + xgv[0 * 2 + nt].f[r]);
          float fv = sigm_f(scl[nt][1] * (float)acc[nt][1][r] + xgv[1 * 2 + nt].f[r]);
          float gv = tanh_f(scl[nt][2] * (float)acc[nt][2][r] + xgv[2 * 2 + nt].f[r]);
          float ov = sigm_f(scl[nt][3] * (float)acc[nt][3][r] + xgv[3 * 2 + nt].f[r]);
          cst[nt][r] = fv * cst[nt][r] + iv * gv;
          float h = ov * tanh_f(cst[nt][r]);
          hv[nt][r] = h;
          if (l == 4 && t == T_ - 1) h4_last[(quad * 4 + r) * H_ + (n0 + nt * 16 + c16)] = h;
        }
      // bf16 pairs -> LLC h ring (streams); drained once per chunk
#pragma unroll
      for (int nt = 0; nt < 2; ++nt)
#pragma unroll
        for (int r = 0; r < 4; ++r) {
          float oth = __shfl_xor(hv[nt][r], 1, 64);
          if ((lane & 1) == 0) {
            unsigned pk = (unsigned)f2bf(hv[nt][r]) | ((unsigned)f2bf(oth) << 16);
            st32(hrw + (size_t)(quad * 4 + r) * H_ + (n0 + nt * 16 + c16), pk);
          }
        }
      // int8 h -> LDS next buffer (fixed scale 127; |h|<=1)
#pragma unroll
      for (int nt = 0; nt < 2; ++nt)
#pragma unroll
        for (int r = 0; r < 4; ++r) {
          int b = quad * 4 + r;
          int q = (int)rintf(hv[nt][r] * 127.f);
          hlds[nbo + ((b * 256 + (n0 + nt * 16 + c16)) ^ ((b & 7) << 4))] = (signed char)q;
        }
      asm volatile("s_waitcnt lgkmcnt(0)" ::: "memory");
      if ((t & 7) == 7) {            // chunk boundary: drain ring stores, publish
        asm volatile("s_waitcnt vmcnt(0)" ::: "memory");
        BAR();
        if (tid == 0) st32(mypf, (unsigned)(t + 1));
      }
      BAR();                          // h(t) LDS buffer complete
    }
  } else {
    // ================= stream roles (512 thr; compute on waves 0-3) =========
    int sb = bid - NRECB, s, j, GSS;
    if (sb < 20)      { s = sb >> 2; j = sb & 3;  GSS = 4; }
    else if (sb < 28) { s = 5;       j = sb - 20; GSS = 8; }
    else              { s = 6;       j = sb - 28; GSS = 8; }
    const bool isXG = (s < 5), isFO = (s == 5), isFI = (s == 6);
    const unsigned short* Bw = wbf + (size_t)(isXG ? s : (isFO ? 5 : 6)) * WELEM;
    const float* bias = isXG ? ((s < 4) ? (b0 + s * NG) : b1) : (isFO ? fo_b : fi_b);
    unsigned int* myprog =
        flags + (isXG ? (FL_XGP(s) + j) : (isFO ? (FL_FOP + j) : (FL_FIP + j)));

    for (int tc = j; tc < NCH; tc += GSS) {
      // output-ring overwrite guard
      if (tc >= WCH) {
        unsigned int tgt = (unsigned)(tc - WCH + 1);
        if (isXG)      { if (tid == 0) spin_ge(flags + FL_PF(s), 8u * tgt); }
        else if (isFO) { if (tid < 8)  spin_ge(flags + FL_FIP + tid, tgt); }
        else           { if (tid < 4)  spin_ge(flags + FL_XGP(4) + tid, tgt); }
      }
      // input readiness
      if (isXG) {
        if (s >= 1 && s <= 3) { if (tid == 0) spin_ge(flags + FL_PF(s - 1), 8u * (unsigned)(tc + 1)); }
        else if (s == 4)      { if (tid == 0) spin_ge(flags + FL_FIF + (tc & 15), (unsigned)(tc + 1)); }
      } else if (isFO) {
        if (tid == 0) spin_ge(flags + FL_PF(3), 8u * (unsigned)(tc + 1));
      } else {
        if (tid == 0) spin_ge(flags + FL_FOF + (tc & 15), (unsigned)(tc + 1));
      }
      __syncthreads();

      if (!isFI) {
        // [128,256] x [256,1024]
#pragma unroll
        for (int m_blk = 0; m_blk < 2; ++m_blk) {
          __syncthreads();
          if (tid < 256) { // stage 64 A rows into LDS (bf16)
            int rloc = tid >> 2;
            int k0 = (tid & 3) * 64;
            int row = m_blk * 64 + rloc;
            int tl = row >> 4, b = row & 15;
            int t = tc * CHUNK + tl;
            unsigned short* dst = &smem[rloc * APITCH + k0];
            if (s == 0) {
              const float* src = x + ((size_t)b * T_ + t) * H_ + k0;
#pragma unroll
              for (int i = 0; i < 16; ++i) {
                f32x4 v = *(const f32x4*)(src + i * 4);
                *(unsigned*)(dst + i * 4)     = (unsigned)f2bf(v[0]) | ((unsigned)f2bf(v[1]) << 16);
                *(unsigned*)(dst + i * 4 + 2) = (unsigned)f2bf(v[2]) | ((unsigned)f2bf(v[3]) << 16);
              }
            } else {
              const unsigned short* src;
              if (isXG && s <= 3)
                src = h_ring + ((size_t)(s - 1) * WH + (size_t)(t & 127)) * (B_ * H_) + b * H_ + k0;
              else if (isXG)  // s==4: fan-in output
                src = fi_ring + ((size_t)(tc & 15) * 128 + row) * H_ + k0;
              else            // FO: h3
                src = h_ring + ((size_t)3 * WH + (size_t)(t & 127)) * (B_ * H_) + b * H_ + k0;
#pragma unroll
              for (int i = 0; i < 16; ++i)
                *(ull*)(dst + i * 4) = ld64((const ull*)src + i);
            }
          }
          __syncthreads();
          if (wave < 4) {
            bf16x8 afr[4][8];
#pragma unroll
            for (int mt = 0; mt < 4; ++mt)
#pragma unroll
              for (int kk = 0; kk < 8; ++kk)
                afr[mt][kk] = *(const bf16x8*)(&smem[(mt * 16 + c16) * APITCH + kk * 32 + quad * 8]);
            for (int nn = 0; nn < 16; ++nn) {
              int n = (wave * 16 + nn) * 16 + c16;
              const unsigned short* bp = Bw + (size_t)n * 256 + quad * 8;
              bf16x8 bfr2[8];
#pragma unroll
              for (int kk = 0; kk < 8; ++kk) bfr2[kk] = *(const bf16x8*)(bp + kk * 32);
              f32x4 ac[4];
#pragma unroll
              for (int mt = 0; mt < 4; ++mt) ac[mt] = (f32x4){0.f, 0.f, 0.f, 0.f};
#pragma unroll
              for (int kk = 0; kk < 8; ++kk)
#pragma unroll
                for (int mt = 0; mt < 4; ++mt)
                  ac[mt] = __builtin_amdgcn_mfma_f32_16x16x32_bf16(afr[mt][kk], bfr2[kk], ac[mt], 0, 0, 0);
              float bn = bias[n];
              if (isXG) {
                ull* xg8 = (ull*)(xg_ring + (size_t)s * WXG * (NG * B_));
#pragma unroll
                for (int mt = 0; mt < 4; ++mt) {
                  int t = tc * CHUNK + m_blk * 4 + mt;
                  size_t bi = ((size_t)(t & 127) * (NG * B_) + (size_t)n * B_ + quad * 4) >> 1;
                  union { ull u; float f[2]; } u0, u1;
                  u0.f[0] = ac[mt][0] + bn; u0.f[1] = ac[mt][1] + bn;
                  u1.f[0] = ac[mt][2] + bn; u1.f[1] = ac[mt][3] + bn;
                  st64(xg8 + bi, u0.u);
                  st64(xg8 + bi + 1, u1.u);
                }
              } else {  // FO: bias + LeakyReLU -> bf16 ring
#pragma unroll
                for (int mt = 0; mt < 4; ++mt) {
                  int row = m_blk * 64 + mt * 16 + quad * 4;
#pragma unroll
                  for (int r = 0; r < 4; ++r) {
                    float v = ac[mt][r] + bn;
                    v = v >= 0.f ? v : 0.2f * v;
                    float oth = __shfl_xor(v, 1, 64);
                    if ((lane & 1) == 0) {
                      unsigned pk = (unsigned)f2bf(v) | ((unsigned)f2bf(oth) << 16);
                      st32(fo_ring + ((size_t)(tc & 15) * 128 + row + r) * F_ + n, pk);
                    }
                  }
                }
              }
            }
          }
        }
      } else {
        // FI: [128,1024] x [1024,256]
        f32x4 acc[2][4][4];
#pragma unroll
        for (int a1 = 0; a1 < 2; ++a1)
#pragma unroll
          for (int a2 = 0; a2 < 4; ++a2)
#pragma unroll
            for (int a3 = 0; a3 < 4; ++a3) acc[a1][a2][a3] = (f32x4){0.f, 0.f, 0.f, 0.f};
#pragma unroll
        for (int ks = 0; ks < 4; ++ks) {
#pragma unroll
          for (int m_blk = 0; m_blk < 2; ++m_blk) {
            __syncthreads();
            if (tid < 256) {
              int rloc = tid >> 2;
              int k0 = (tid & 3) * 64;
              int row = m_blk * 64 + rloc;
              const unsigned short* src =
                  fo_ring + ((size_t)(tc & 15) * 128 + row) * F_ + ks * 256 + k0;
              unsigned short* dst = &smem[rloc * APITCH + k0];
#pragma unroll
              for (int i = 0; i < 16; ++i)
                *(ull*)(dst + i * 4) = ld64((const ull*)src + i);
            }
            __syncthreads();
            if (wave < 4) {
              bf16x8 afr[4][8];
#pragma unroll
              for (int mt = 0; mt < 4; ++mt)
#pragma unroll
                for (int kk = 0; kk < 8; ++kk)
                  afr[mt][kk] = *(const bf16x8*)(&smem[(mt * 16 + c16) * APITCH + kk * 32 + quad * 8]);
#pragma unroll
              for (int nn = 0; nn < 4; ++nn) {
                int n = (wave * 4 + nn) * 16 + c16;
                const unsigned short* bp = Bw + (size_t)n * 1024 + ks * 256 + quad * 8;
                bf16x8 bfr2[8];
#pragma unroll
                for (int kk = 0; kk < 8; ++kk) bfr2[kk] = *(const bf16x8*)(bp + kk * 32);
#pragma unroll
                for (int kk = 0; kk < 8; ++kk)
#pragma unroll
                  for (int mt = 0; mt < 4; ++mt)
                    acc[m_blk][nn][mt] =
                        __builtin_amdgcn_mfma_f32_16x16x32_bf16(afr[mt][kk], bfr2[kk], acc[m_blk][nn][mt], 0, 0, 0);
              }
            }
          }
        }
        if (wave < 4) {
#pragma unroll
          for (int m_blk = 0; m_blk < 2; ++m_blk)
#pragma unroll
            for (int nn = 0; nn < 4; ++nn) {
              int n = (wave * 4 + nn) * 16 + c16;
              float bn = bias[n];
#pragma unroll
              for (int mt = 0; mt < 4; ++mt) {
                int row = m_blk * 64 + mt * 16 + quad * 4;
#pragma unroll
                for (int r = 0; r < 4; ++r) {
                  float v = acc[m_blk][nn][mt][r] + bn;
                  float oth = __shfl_xor(v, 1, 64);
                  if ((lane & 1) == 0) {
                    unsigned pk = (unsigned)f2bf(v) | ((unsigned)f2bf(oth) << 16);
                    st32(fi_ring + ((size_t)(tc & 15) * 128 + row + r) * H_ + n, pk);
                  }
                }
              }
            }
        }
      }
      __syncthreads();   // drains all waves' ring stores before flag publish
      if (tid == 0) {
        unsigned int* fl = isXG ? (flags + FL_XGF(s) + (tc & 15))
                                : (isFO ? (flags + FL_FOF + (tc & 15)) : (flags + FL_FIF + (tc & 15)));
        st32(fl, (unsigned)(tc + 1));
        st32(myprog, (unsigned)(tc + 1));
      }
    }
  }
}

// ---------------------------------------------------------------------------
__global__ void k_head(const float* __restrict__ hW, const float* __restrict__ hb,
                       unsigned char* ws, float* __restrict__ out) {
  __shared__ float red[256];
  const float* h4 = (const float*)(ws + OFF_H4);
  int tid = threadIdx.x;
  int b = tid >> 4, k0 = tid & 15;
  float sum = 0.f;
  for (int k = k0; k < H_; k += 16) sum += h4[b * H_ + k] * hW[k];
  red[tid] = sum;
  __syncthreads();
  if (tid < B_) {
    float z = hb[0];
    for (int i = 0; i < 16; ++i) z += red[tid * 16 + i];
    out[tid] = 1.0f / (1.0f + __expf(-z));
  }
}

// ---------------------------------------------------------------------------
extern "C" void kernel_launch(void* const* d_in, const int* in_sizes, int n_in,
                              void* d_out, int out_size, void* d_ws, size_t ws_size,
                              hipStream_t stream) {
  const float* x    = (const float*)d_in[0];
  const float* w0ih = (const float*)d_in[1];
  const float* w0hh = (const float*)d_in[2];
  const float* b0   = (const float*)d_in[3];
  const float* foW  = (const float*)d_in[4];
  const float* fob  = (const float*)d_in[5];
  const float* fiW  = (const float*)d_in[6];
  const float* fib  = (const float*)d_in[7];
  const float* w1ih = (const float*)d_in[8];
  const float* w1hh = (const float*)d_in[9];
  const float* b1   = (const float*)d_in[10];
  const float* hW   = (const float*)d_in[11];
  const float* hb   = (const float*)d_in[12];
  unsigned char* ws = (unsigned char*)d_ws;
  (void)in_sizes; (void)n_in; (void)out_size; (void)ws_size;

  hipLaunchKernelGGL(k_prep, dim3(7168), dim3(256), 0, stream, w0ih, w1ih, foW, fiW, w0hh, w1hh, ws);
  hipLaunchKernelGGL(k_pipe, dim3(NBLK), dim3(512), 0, stream,
                     x, b0, fob, fib, b1, ws);
  hipLaunchKernelGGL(k_head, dim3(1), dim3(256), 0, stream, hW, hb, ws, (float*)d_out);
}